// Round 11
// baseline (256.687 us; speedup 1.0000x reference)
//
#include <hip/hip_runtime.h>

// Mamba block, MI355X. Round 11: out_proj atomic-accumulate.
//  - k1's LN section also writes out = x (row already in registers, free)
//  - k9 out_proj splitK4 does unsafeAtomicAdd(f32) straight into out
//    -> kills the 16+16 MB partial round-trip and the out_comb dispatch.
// 9 dispatches:
//  k1 convert_ln(+out=x)  k2 gemm128 in_proj  k3 conv_silu  k4 x_proj splitK4
//  k5 dtgemm_fused  k6 scan_pass1  k7 scan_combine  k8 scan_pass2
//  k9 gemm128_atomic out_proj splitK4 -> out += y @ Wo^T

typedef unsigned short u16;
typedef unsigned int u32;

typedef __bf16 bf16x8 __attribute__((ext_vector_type(8)));
typedef float f32x4 __attribute__((ext_vector_type(4)));

#define SCAN_G 32
#define SCAN_T 32
#define NSTATE 65536

#if __has_builtin(__builtin_amdgcn_exp2f)
#define EXP2F(x) __builtin_amdgcn_exp2f(x)
#else
#define EXP2F(x) exp2f(x)
#endif
#define LOG2E 1.44269504f

__device__ __forceinline__ u16 f2bf(float f) {
  u32 u = __float_as_uint(f);
  u32 r = u + 0x7FFFu + ((u >> 16) & 1u);  // RNE
  return (u16)(r >> 16);
}
__device__ __forceinline__ float bf2f(u16 v) {
  return __uint_as_float(((u32)v) << 16);
}

__device__ __forceinline__ void lds_load16(const u16* g, u16* l) {
  __builtin_amdgcn_global_load_lds(
      (const __attribute__((address_space(1))) u32*)g,
      (__attribute__((address_space(3))) u32*)l, 16, 0, 0);
}

// ---------------- k1: vec4 weight converts + LayerNorm + out=x --------------
__global__ __launch_bounds__(256) void convert_ln_kernel(
    const float* __restrict__ w0, const float* __restrict__ w1,
    const float* __restrict__ w2, const float* __restrict__ w3,
    u16* __restrict__ o0, u16* __restrict__ o1,
    u16* __restrict__ o2, u16* __restrict__ o3,
    const float* __restrict__ x, const float* __restrict__ nw,
    const float* __restrict__ nb, u16* __restrict__ h,
    float* __restrict__ out) {
  const int bx = blockIdx.x;
  const int tid = threadIdx.x;
  if (bx < 6464) {
    const int q = bx * 256 + tid;
    const float4* src;
    ushort4* dst;
    int off;
    if (q < 1048576) { src = (const float4*)w0; dst = (ushort4*)o0; off = q; }
    else if (q < 1097728) { src = (const float4*)w1; dst = (ushort4*)o1; off = q - 1048576; }
    else if (q < 1130496) { src = (const float4*)w2; dst = (ushort4*)o2; off = q - 1097728; }
    else { src = (const float4*)w3; dst = (ushort4*)o3; off = q - 1130496; }
    const float4 v = src[off];
    ushort4 o;
    o.x = f2bf(v.x); o.y = f2bf(v.y); o.z = f2bf(v.z); o.w = f2bf(v.w);
    dst[off] = o;
    return;
  }
  const int row = bx - 6464;
  const float4 v = ((const float4*)(x + (size_t)row * 1024))[tid];
  // residual pre-init: out = x (row already in registers)
  ((float4*)(out + (size_t)row * 1024))[tid] = v;
  float s = v.x + v.y + v.z + v.w;
  float s2 = v.x * v.x + v.y * v.y + v.z * v.z + v.w * v.w;
  for (int off = 32; off >= 1; off >>= 1) {
    s += __shfl_xor(s, off);
    s2 += __shfl_xor(s2, off);
  }
  __shared__ float red[8];
  const int wave = tid >> 6;
  if ((tid & 63) == 0) { red[wave * 2] = s; red[wave * 2 + 1] = s2; }
  __syncthreads();
  s = red[0] + red[2] + red[4] + red[6];
  s2 = red[1] + red[3] + red[5] + red[7];
  const float mu = s * (1.0f / 1024.0f);
  const float var = s2 * (1.0f / 1024.0f) - mu * mu;
  const float rstd = rsqrtf(var + 1e-5f);
  const float4 wv = ((const float4*)nw)[tid];
  const float4 bv = ((const float4*)nb)[tid];
  ushort4 o;
  o.x = f2bf((v.x - mu) * rstd * wv.x + bv.x);
  o.y = f2bf((v.y - mu) * rstd * wv.y + bv.y);
  o.z = f2bf((v.z - mu) * rstd * wv.z + bv.z);
  o.w = f2bf((v.w - mu) * rstd * wv.w + bv.w);
  ((ushort4*)(h + (size_t)row * 1024))[tid] = o;
}

// ---------------- gemm128 tile body (m97 structure) ----------------
// ATOMIC=false: bf16 store to Cout. ATOMIC=true: f32 atomic add into Cout.
template <bool ATOMIC>
__device__ __forceinline__ void gemm128_body(
    const u16* A, const u16* W, void* Cout, int N, int K,
    int m0, int n0, int kOff, int kLen, u16* As, u16* Ws) {
  const int tid = threadIdx.x;
  const int wave = tid >> 6;
  const int lane = tid & 63;
  const int wm = (wave >> 1) * 64;
  const int wn = (wave & 1) * 64;
  f32x4 acc[4][4];
#pragma unroll
  for (int i = 0; i < 4; ++i)
#pragma unroll
    for (int j = 0; j < 4; ++j) acc[i][j] = (f32x4){0.f, 0.f, 0.f, 0.f};
  const int fm = lane & 15;
  const int fk = (lane >> 4) * 8;
  const int sr = lane >> 2;
  const int sc = (lane & 3) * 8;
  const u16* gA = A + (size_t)(m0 + wave * 32 + sr) * K + kOff + sc;
  const u16* gB = W + (size_t)(n0 + wave * 32 + sr) * K + kOff + sc;
  u16* lA = As + wave * 1024;
  u16* lB = Ws + wave * 1024;

  for (int kk = 0; kk < kLen; kk += 32) {
    __syncthreads();
    lds_load16(gA + kk, lA);
    lds_load16(gA + (size_t)16 * K + kk, lA + 512);
    lds_load16(gB + kk, lB);
    lds_load16(gB + (size_t)16 * K + kk, lB + 512);
    __syncthreads();
    bf16x8 af[4], bfr[4];
#pragma unroll
    for (int i = 0; i < 4; ++i)
      af[i] = *(const bf16x8*)(As + (wm + i * 16 + fm) * 32 + fk);
#pragma unroll
    for (int j = 0; j < 4; ++j)
      bfr[j] = *(const bf16x8*)(Ws + (wn + j * 16 + fm) * 32 + fk);
#pragma unroll
    for (int i = 0; i < 4; ++i)
#pragma unroll
      for (int j = 0; j < 4; ++j)
        acc[i][j] = __builtin_amdgcn_mfma_f32_16x16x32_bf16(af[i], bfr[j], acc[i][j], 0, 0, 0);
  }
  const int col = lane & 15;
  const int rb = (lane >> 4) * 4;
#pragma unroll
  for (int i = 0; i < 4; ++i)
#pragma unroll
    for (int j = 0; j < 4; ++j)
#pragma unroll
      for (int r = 0; r < 4; ++r) {
        const int m = m0 + wm + i * 16 + rb + r;
        const int n = n0 + wn + j * 16 + col;
        if (ATOMIC)
          unsafeAtomicAdd((float*)Cout + (size_t)m * N + n, acc[i][j][r]);
        else
          ((u16*)Cout)[(size_t)m * N + n] = f2bf(acc[i][j][r]);
      }
}

// k2: in_proj direct, bf16 out
__global__ __launch_bounds__(256) void gemm128_kernel(
    const u16* __restrict__ A, const u16* __restrict__ W,
    u16* __restrict__ Cout, int M, int N, int K) {
  __shared__ u16 As[128 * 32];
  __shared__ u16 Ws[128 * 32];
  gemm128_body<false>(A, W, Cout, N, K, blockIdx.y * 128, blockIdx.x * 128,
                      0, K, As, Ws);
}

// k9: out_proj splitK4, atomic f32 accumulate into out (pre-inited to x)
__global__ __launch_bounds__(256) void gemm128_atomic_kernel(
    const u16* __restrict__ A, const u16* __restrict__ W,
    float* __restrict__ out, int M, int N, int K) {
  __shared__ u16 As[128 * 32];
  __shared__ u16 Ws[128 * 32];
  const int kLen = K / 4;
  gemm128_body<true>(A, W, out, N, K, blockIdx.y * 128, blockIdx.x * 128,
                     blockIdx.z * kLen, kLen, As, Ws);
}

// ---------------- k3: conv + silu, vec4 channels ----------------
__global__ __launch_bounds__(256) void conv_silu_kernel(
    const u16* __restrict__ xzb, const float* __restrict__ cw,
    const float* __restrict__ cb, u16* __restrict__ xcb) {
  const int u = blockIdx.x * 256 + threadIdx.x;  // over M * 512
  const int d4 = (u & 511) * 4;
  const int m = u >> 9;
  const int l = m & 1023;
  const float4 wv0 = ((const float4*)cw)[d4];
  const float4 wv1 = ((const float4*)cw)[d4 + 1];
  const float4 wv2 = ((const float4*)cw)[d4 + 2];
  const float4 wv3 = ((const float4*)cw)[d4 + 3];
  const float4 cbv = ((const float4*)cb)[u & 511];
  float a0 = cbv.x, a1 = cbv.y, a2 = cbv.z, a3 = cbv.w;
  const float wk[4][4] = {{wv0.x, wv0.y, wv0.z, wv0.w},
                          {wv1.x, wv1.y, wv1.z, wv1.w},
                          {wv2.x, wv2.y, wv2.z, wv2.w},
                          {wv3.x, wv3.y, wv3.z, wv3.w}};
#pragma unroll
  for (int k = 0; k < 4; ++k) {
    if (l + k - 3 >= 0) {
      const ushort4 xv = *(const ushort4*)&xzb[(size_t)(m + k - 3) * 4096 + d4];
      a0 += bf2f(xv.x) * wk[0][k];
      a1 += bf2f(xv.y) * wk[1][k];
      a2 += bf2f(xv.z) * wk[2][k];
      a3 += bf2f(xv.w) * wk[3][k];
    }
  }
  ushort4 o;
  o.x = f2bf(a0 / (1.0f + __expf(-a0)));
  o.y = f2bf(a1 / (1.0f + __expf(-a1)));
  o.z = f2bf(a2 / (1.0f + __expf(-a2)));
  o.w = f2bf(a3 / (1.0f + __expf(-a3)));
  *(ushort4*)&xcb[(size_t)m * 2048 + d4] = o;
}

// ---------------- k4: x_proj 64-tile splitK4 -> f32 slabs ----------------
__global__ __launch_bounds__(256) void gemm_bt_kernel(
    const u16* __restrict__ A, const u16* __restrict__ W,
    float* __restrict__ C, int M, int N, int K) {
  const int n0 = blockIdx.x * 64;
  const int m0 = blockIdx.y * 64;
  const int ks = blockIdx.z;
  const int kLen = K / 4;
  const int kOff = ks * kLen;
  __shared__ u16 As[64 * 32];
  __shared__ u16 Ws[64 * 32];
  const int tid = threadIdx.x;
  const int wave = tid >> 6;
  const int lane = tid & 63;
  const int wm = (wave >> 1) * 32;
  const int wn = (wave & 1) * 32;
  const int lrow = tid >> 2;
  const int lcg = (tid & 3) * 8;
  f32x4 acc[2][2];
#pragma unroll
  for (int i = 0; i < 2; ++i)
#pragma unroll
    for (int j = 0; j < 2; ++j) acc[i][j] = (f32x4){0.f, 0.f, 0.f, 0.f};
  const int fm = lane & 15;
  const int fk = (lane >> 4) * 8;
  const int wrow = n0 + lrow;
  for (int k0 = kOff; k0 < kOff + kLen; k0 += 32) {
    uint4 av = *(const uint4*)(A + (size_t)(m0 + lrow) * K + k0 + lcg);
    uint4 wv = make_uint4(0u, 0u, 0u, 0u);
    if (wrow < N) wv = *(const uint4*)(W + (size_t)wrow * K + k0 + lcg);
    __syncthreads();
    *(uint4*)(As + lrow * 32 + lcg) = av;
    *(uint4*)(Ws + lrow * 32 + lcg) = wv;
    __syncthreads();
    bf16x8 a0 = *(const bf16x8*)(As + (wm + fm) * 32 + fk);
    bf16x8 a1 = *(const bf16x8*)(As + (wm + 16 + fm) * 32 + fk);
    bf16x8 b0 = *(const bf16x8*)(Ws + (wn + fm) * 32 + fk);
    bf16x8 b1 = *(const bf16x8*)(Ws + (wn + 16 + fm) * 32 + fk);
    acc[0][0] = __builtin_amdgcn_mfma_f32_16x16x32_bf16(a0, b0, acc[0][0], 0, 0, 0);
    acc[0][1] = __builtin_amdgcn_mfma_f32_16x16x32_bf16(a0, b1, acc[0][1], 0, 0, 0);
    acc[1][0] = __builtin_amdgcn_mfma_f32_16x16x32_bf16(a1, b0, acc[1][0], 0, 0, 0);
    acc[1][1] = __builtin_amdgcn_mfma_f32_16x16x32_bf16(a1, b1, acc[1][1], 0, 0, 0);
  }
  const int col = lane & 15;
  const int rbase = (lane >> 4) * 4;
#pragma unroll
  for (int tm = 0; tm < 2; ++tm)
#pragma unroll
    for (int tn = 0; tn < 2; ++tn)
#pragma unroll
      for (int r = 0; r < 4; ++r) {
        int m = m0 + wm + tm * 16 + rbase + r;
        int n = n0 + wn + tn * 16 + col;
        if (n < N)
          C[(size_t)ks * M * N + (size_t)m * N + n] = acc[tm][tn][r];
      }
}

// ---------------- k5: dt GEMM fused (comb + softplus -> bf16 dt) ------------
__global__ __launch_bounds__(256) void dtgemm_fused_kernel(
    const float* __restrict__ xpart, const u16* __restrict__ Wdt,
    const float* __restrict__ bias, u16* __restrict__ dtb,
    float* __restrict__ xdbl) {
  const int K = 64;
  const int n0 = blockIdx.x * 64;
  const int m0 = blockIdx.y * 64;
  const int tid = threadIdx.x;
  if (blockIdx.x == 0) {
#pragma unroll
    for (int j = 0; j < 8; ++j) {
      const int e = tid * 8 + j;
      const size_t ix = (size_t)(m0 + (e >> 5)) * 96 + 64 + (e & 31);
      xdbl[ix] = xpart[ix] + xpart[ix + 196608] + xpart[ix + 2 * 196608] +
                 xpart[ix + 3 * 196608];
    }
  }
  __shared__ u16 As[64 * 32];
  __shared__ u16 Ws[64 * 32];
  const int wave = tid >> 6;
  const int lane = tid & 63;
  const int wm = (wave >> 1) * 32;
  const int wn = (wave & 1) * 32;
  const int lrow = tid >> 2;
  const int lcg = (tid & 3) * 8;
  f32x4 acc[2][2];
#pragma unroll
  for (int i = 0; i < 2; ++i)
#pragma unroll
    for (int j = 0; j < 2; ++j) acc[i][j] = (f32x4){0.f, 0.f, 0.f, 0.f};
  const int fm = lane & 15;
  const int fk = (lane >> 4) * 8;
  for (int k0 = 0; k0 < K; k0 += 32) {
    const size_t ab = (size_t)(m0 + lrow) * 96 + k0 + lcg;
    float av[8];
#pragma unroll
    for (int t = 0; t < 2; ++t) {
      float4 v0 = *(const float4*)&xpart[ab + t * 4];
      float4 v1 = *(const float4*)&xpart[ab + 196608 + t * 4];
      float4 v2 = *(const float4*)&xpart[ab + 2 * 196608 + t * 4];
      float4 v3 = *(const float4*)&xpart[ab + 3 * 196608 + t * 4];
      av[t * 4 + 0] = v0.x + v1.x + v2.x + v3.x;
      av[t * 4 + 1] = v0.y + v1.y + v2.y + v3.y;
      av[t * 4 + 2] = v0.z + v1.z + v2.z + v3.z;
      av[t * 4 + 3] = v0.w + v1.w + v2.w + v3.w;
    }
    ushort4 ap0, ap1;
    ap0.x = f2bf(av[0]); ap0.y = f2bf(av[1]); ap0.z = f2bf(av[2]); ap0.w = f2bf(av[3]);
    ap1.x = f2bf(av[4]); ap1.y = f2bf(av[5]); ap1.z = f2bf(av[6]); ap1.w = f2bf(av[7]);
    uint4 wv = *(const uint4*)(Wdt + (size_t)(n0 + lrow) * K + k0 + lcg);
    __syncthreads();
    *(ushort4*)(As + lrow * 32 + lcg) = ap0;
    *(ushort4*)(As + lrow * 32 + lcg + 4) = ap1;
    *(uint4*)(Ws + lrow * 32 + lcg) = wv;
    __syncthreads();
    bf16x8 a0 = *(const bf16x8*)(As + (wm + fm) * 32 + fk);
    bf16x8 a1 = *(const bf16x8*)(As + (wm + 16 + fm) * 32 + fk);
    bf16x8 b0 = *(const bf16x8*)(Ws + (wn + fm) * 32 + fk);
    bf16x8 b1 = *(const bf16x8*)(Ws + (wn + 16 + fm) * 32 + fk);
    acc[0][0] = __builtin_amdgcn_mfma_f32_16x16x32_bf16(a0, b0, acc[0][0], 0, 0, 0);
    acc[0][1] = __builtin_amdgcn_mfma_f32_16x16x32_bf16(a0, b1, acc[0][1], 0, 0, 0);
    acc[1][0] = __builtin_amdgcn_mfma_f32_16x16x32_bf16(a1, b0, acc[1][0], 0, 0, 0);
    acc[1][1] = __builtin_amdgcn_mfma_f32_16x16x32_bf16(a1, b1, acc[1][1], 0, 0, 0);
  }
  const int col = lane & 15;
  const int rbase = (lane >> 4) * 4;
#pragma unroll
  for (int tm = 0; tm < 2; ++tm)
#pragma unroll
    for (int tn = 0; tn < 2; ++tn)
#pragma unroll
      for (int r = 0; r < 4; ++r) {
        const int m = m0 + wm + tm * 16 + rbase + r;
        const int n = n0 + wn + tn * 16 + col;
        float v = acc[tm][tn][r] + bias[n];
        v = (v > 20.f) ? v : log1pf(__expf(v));
        dtb[(size_t)m * 2048 + n] = f2bf(v);
      }
}

// ---------------- k6-k8: register-state chunked scan ----------------
__global__ __launch_bounds__(256) void scan_pass1_kernel(
    const u16* __restrict__ dtb, const u16* __restrict__ xcb,
    const float* __restrict__ xdbl, const float* __restrict__ A_log,
    float* __restrict__ hend, float* __restrict__ prodA) {
  const int bx = blockIdx.x;
  const int d0 = (bx & 7) * 256;
  const int b = (bx >> 3) & 1;
  const int g = bx >> 4;
  const int tid = threadIdx.x;
  const int d = d0 + tid;
  const int mb = b * 1024 + g * SCAN_T;
  float a2[16];
#pragma unroll
  for (int q = 0; q < 4; ++q) {
    float4 al = *(const float4*)&A_log[(size_t)d * 16 + q * 4];
    a2[q * 4 + 0] = -__expf(al.x) * LOG2E;
    a2[q * 4 + 1] = -__expf(al.y) * LOG2E;
    a2[q * 4 + 2] = -__expf(al.z) * LOG2E;
    a2[q * 4 + 3] = -__expf(al.w) * LOG2E;
  }
  float h[16];
#pragma unroll
  for (int n = 0; n < 16; ++n) h[n] = 0.f;
  float cs = 0.f;
  const u16* dp = dtb + (size_t)mb * 2048 + d;
  const u16* xp = xcb + (size_t)mb * 2048 + d;
  const float* xb = xdbl + (size_t)mb * 96 + 64;
#pragma unroll 4
  for (int s = 0; s < SCAN_T; ++s) {
    const float dtv = bf2f(dp[(size_t)s * 2048]);
    const float xcv = bf2f(xp[(size_t)s * 2048]);
    const float du = dtv * xcv;
    const float4 B0 = *(const float4*)(xb + (size_t)s * 96 + 0);
    const float4 B1 = *(const float4*)(xb + (size_t)s * 96 + 4);
    const float4 B2 = *(const float4*)(xb + (size_t)s * 96 + 8);
    const float4 B3 = *(const float4*)(xb + (size_t)s * 96 + 12);
    const float Bv[16] = {B0.x, B0.y, B0.z, B0.w, B1.x, B1.y, B1.z, B1.w,
                          B2.x, B2.y, B2.z, B2.w, B3.x, B3.y, B3.z, B3.w};
#pragma unroll
    for (int n = 0; n < 16; ++n) {
      const float da = EXP2F(dtv * a2[n]);
      h[n] = __builtin_fmaf(da, h[n], du * Bv[n]);
    }
    cs += dtv;
  }
  const size_t base = ((size_t)(g * 2 + b) * 2048 + d) * 16;
#pragma unroll
  for (int q = 0; q < 4; ++q) {
    float4 hv = {h[q * 4], h[q * 4 + 1], h[q * 4 + 2], h[q * 4 + 3]};
    *(float4*)&hend[base + q * 4] = hv;
    float4 pv = {EXP2F(a2[q * 4] * cs), EXP2F(a2[q * 4 + 1] * cs),
                 EXP2F(a2[q * 4 + 2] * cs), EXP2F(a2[q * 4 + 3] * cs)};
    *(float4*)&prodA[base + q * 4] = pv;
  }
}

__global__ __launch_bounds__(256) void scan_combine_kernel(
    const float* __restrict__ hend, const float* __restrict__ prodA,
    float* __restrict__ hinit) {
  const int sid = blockIdx.x * 256 + threadIdx.x;
  float H = 0.f;
#pragma unroll 8
  for (int g = 0; g < SCAN_G; ++g) {
    hinit[g * NSTATE + sid] = H;
    H = prodA[g * NSTATE + sid] * H + hend[g * NSTATE + sid];
  }
}

__global__ __launch_bounds__(256) void scan_pass2_kernel(
    const u16* __restrict__ dtb, const u16* __restrict__ xcb,
    const u16* __restrict__ xzb, const float* __restrict__ xdbl,
    const float* __restrict__ A_log, const float* __restrict__ Dsk,
    const float* __restrict__ hinit, u16* __restrict__ yb) {
  const int bx = blockIdx.x;
  const int d0 = (bx & 7) * 256;
  const int b = (bx >> 3) & 1;
  const int g = bx >> 4;
  const int tid = threadIdx.x;
  const int d = d0 + tid;
  const int mb = b * 1024 + g * SCAN_T;
  float a2[16];
#pragma unroll
  for (int q = 0; q < 4; ++q) {
    float4 al = *(const float4*)&A_log[(size_t)d * 16 + q * 4];
    a2[q * 4 + 0] = -__expf(al.x) * LOG2E;
    a2[q * 4 + 1] = -__expf(al.y) * LOG2E;
    a2[q * 4 + 2] = -__expf(al.z) * LOG2E;
    a2[q * 4 + 3] = -__expf(al.w) * LOG2E;
  }
  const float Dd = Dsk[d];
  float h[16];
  {
    const float* hi = hinit + ((size_t)(g * 2 + b) * 2048 + d) * 16;
#pragma unroll
    for (int q = 0; q < 4; ++q) {
      float4 hv = *(const float4*)(hi + q * 4);
      h[q * 4] = hv.x; h[q * 4 + 1] = hv.y; h[q * 4 + 2] = hv.z; h[q * 4 + 3] = hv.w;
    }
  }
  const u16* dp = dtb + (size_t)mb * 2048 + d;
  const u16* xp = xcb + (size_t)mb * 2048 + d;
  const u16* zp = xzb + (size_t)mb * 4096 + 2048 + d;
  const float* xb = xdbl + (size_t)mb * 96 + 64;
  u16* yp = yb + (size_t)mb * 2048 + d;
#pragma unroll 2
  for (int s = 0; s < SCAN_T; ++s) {
    const float dtv = bf2f(dp[(size_t)s * 2048]);
    const float xcv = bf2f(xp[(size_t)s * 2048]);
    const float du = dtv * xcv;
    const float4 B0 = *(const float4*)(xb + (size_t)s * 96 + 0);
    const float4 B1 = *(const float4*)(xb + (size_t)s * 96 + 4);
    const float4 B2 = *(const float4*)(xb + (size_t)s * 96 + 8);
    const float4 B3 = *(const float4*)(xb + (size_t)s * 96 + 12);
    const float4 C0 = *(const float4*)(xb + (size_t)s * 96 + 16);
    const float4 C1 = *(const float4*)(xb + (size_t)s * 96 + 20);
    const float4 C2 = *(const float4*)(xb + (size_t)s * 96 + 24);
    const float4 C3 = *(const float4*)(xb + (size_t)s * 96 + 28);
    const float Bv[16] = {B0.x, B0.y, B0.z, B0.w, B1.x, B1.y, B1.z, B1.w,
                          B2.x, B2.y, B2.z, B2.w, B3.x, B3.y, B3.z, B3.w};
    const float Cv[16] = {C0.x, C0.y, C0.z, C0.w, C1.x, C1.y, C1.z, C1.w,
                          C2.x, C2.y, C2.z, C2.w, C3.x, C3.y, C3.z, C3.w};
    float y = 0.f;
#pragma unroll
    for (int n = 0; n < 16; ++n) {
      const float da = EXP2F(dtv * a2[n]);
      h[n] = __builtin_fmaf(da, h[n], du * Bv[n]);
      y = __builtin_fmaf(h[n], Cv[n], y);
    }
    const float zv = bf2f(zp[(size_t)s * 4096]);
    const float sig = 1.0f / (1.0f + EXP2F(-zv * LOG2E));
    const float yv = (y + xcv * Dd) * (zv * sig);
    yp[(size_t)s * 2048] = f2bf(yv);
  }
}

// ---------------- launch ----------------
extern "C" void kernel_launch(void* const* d_in, const int* in_sizes, int n_in,
                              void* d_out, int out_size, void* d_ws, size_t ws_size,
                              hipStream_t stream) {
  const float* x        = (const float*)d_in[0];
  const float* norm_w   = (const float*)d_in[1];
  const float* norm_b   = (const float*)d_in[2];
  const float* in_projw = (const float*)d_in[3];
  const float* conv_w   = (const float*)d_in[4];
  const float* conv_b   = (const float*)d_in[5];
  const float* x_projw  = (const float*)d_in[6];
  const float* dt_projw = (const float*)d_in[7];
  const float* dt_projb = (const float*)d_in[8];
  const float* A_log    = (const float*)d_in[9];
  const float* D_skip   = (const float*)d_in[10];
  const float* out_projw= (const float*)d_in[11];
  float* out = (float*)d_out;

  char* p = (char*)d_ws;
  auto alloc = [&](size_t bytes) {
    char* r = p;
    p += (bytes + 255) & ~(size_t)255;
    return r;
  };
  u16* xzb    = (u16*)alloc(2048ULL * 4096 * 2);   // 16 MB
  u16* xcb    = (u16*)alloc(2048ULL * 2048 * 2);   // 8 MB
  u16* dtb16  = (u16*)alloc(2048ULL * 2048 * 2);   // 8 MB
  float* xdbl = (float*)alloc(2048ULL * 96 * 4);   // 768 KB
  u16* h_bf   = (u16*)alloc(2048ULL * 1024 * 2);   // 4 MB
  u16* ybf    = (u16*)alloc(2048ULL * 2048 * 2);   // 8 MB
  u16* Wi     = (u16*)alloc(4096ULL * 1024 * 2);   // 8 MB
  u16* Wx     = (u16*)alloc(96ULL * 2048 * 2);     // 384 KB
  u16* Wdt    = (u16*)alloc(2048ULL * 64 * 2);     // 256 KB
  u16* Wo     = (u16*)alloc(1024ULL * 2048 * 2);   // 4 MB
  float* hend = (float*)alloc((size_t)SCAN_G * NSTATE * 4);  // 8 MB
  float* prodA= (float*)alloc((size_t)SCAN_G * NSTATE * 4);  // 8 MB
  float* hinit= (float*)alloc((size_t)SCAN_G * NSTATE * 4);  // 8 MB
  float* xpart= (float*)alloc(4ULL * 2048 * 96 * 4);         // 3 MB
  (void)ws_size; (void)in_sizes; (void)n_in; (void)out_size;

  // k1: vec4 weight converts + layernorm + out=x
  convert_ln_kernel<<<8512, 256, 0, stream>>>(in_projw, x_projw, dt_projw,
                                              out_projw, Wi, Wx, Wdt, Wo,
                                              x, norm_w, norm_b, h_bf, out);

  // k2: xz = h @ in_proj_w^T  [2048,4096] -> bf16 (512 blocks)
  gemm128_kernel<<<dim3(32, 16), 256, 0, stream>>>(h_bf, Wi, xzb, 2048, 4096, 1024);

  // k3: conv + silu -> xc bf16 (vec4)
  conv_silu_kernel<<<4096, 256, 0, stream>>>(xzb, conv_w, conv_b, xcb);

  // k4: x_dbl partials = xc @ x_proj_w^T  [2048,96], splitK=4
  gemm_bt_kernel<<<dim3(2, 32, 4), 256, 0, stream>>>(xcb, Wx, xpart, 2048, 96, 2048);

  // k5: dt gemm fused (comb + softplus -> bf16 dt; writes xdbl B/C)
  dtgemm_fused_kernel<<<dim3(32, 32), 256, 0, stream>>>(xpart, Wdt, dt_projb,
                                                        dtb16, xdbl);

  // k6-k8: chunked selective scan
  scan_pass1_kernel<<<512, 256, 0, stream>>>(dtb16, xcb, xdbl, A_log, hend, prodA);
  scan_combine_kernel<<<256, 256, 0, stream>>>(hend, prodA, hinit);
  scan_pass2_kernel<<<512, 256, 0, stream>>>(dtb16, xcb, xzb, xdbl, A_log,
                                             D_skip, hinit, ybf);

  // k9: out += y @ out_proj_w^T  [2048,1024], splitK=4, f32 atomic accumulate
  gemm128_atomic_kernel<<<dim3(8, 16, 4), 256, 0, stream>>>(ybf, Wo, out,
                                                            2048, 1024, 2048);
}

// Round 12
// 240.932 us; speedup vs baseline: 1.0654x; 1.0654x over previous
//
#include <hip/hip_runtime.h>

// Mamba block, MI355X. Round 12: revert to Round 10 (measured best, 242.1 us).
// R11's atomic out_proj regressed +14.6us (2M device-scope f32 atomics with
// 4-way cross-XCD line contention) -- splitK partials + combine is cheaper.
// 10 dispatches:
//  k1 convert_ln  k2 gemm128 in_proj  k3 conv_silu  k4 x_proj splitK4
//  k5 dtgemm_fused  k6 scan_pass1  k7 scan_combine  k8 scan_pass2
//  k9 gemm128 out_proj splitK4 -> bf16 partials (alias xzb)  k10 out_comb

typedef unsigned short u16;
typedef unsigned int u32;

typedef __bf16 bf16x8 __attribute__((ext_vector_type(8)));
typedef float f32x4 __attribute__((ext_vector_type(4)));

#define SCAN_G 32
#define SCAN_T 32
#define NSTATE 65536

#if __has_builtin(__builtin_amdgcn_exp2f)
#define EXP2F(x) __builtin_amdgcn_exp2f(x)
#else
#define EXP2F(x) exp2f(x)
#endif
#define LOG2E 1.44269504f

__device__ __forceinline__ u16 f2bf(float f) {
  u32 u = __float_as_uint(f);
  u32 r = u + 0x7FFFu + ((u >> 16) & 1u);  // RNE
  return (u16)(r >> 16);
}
__device__ __forceinline__ float bf2f(u16 v) {
  return __uint_as_float(((u32)v) << 16);
}

__device__ __forceinline__ void lds_load16(const u16* g, u16* l) {
  __builtin_amdgcn_global_load_lds(
      (const __attribute__((address_space(1))) u32*)g,
      (__attribute__((address_space(3))) u32*)l, 16, 0, 0);
}

// ---------------- k1: vec4 weight converts + LayerNorm ----------------
__global__ __launch_bounds__(256) void convert_ln_kernel(
    const float* __restrict__ w0, const float* __restrict__ w1,
    const float* __restrict__ w2, const float* __restrict__ w3,
    u16* __restrict__ o0, u16* __restrict__ o1,
    u16* __restrict__ o2, u16* __restrict__ o3,
    const float* __restrict__ x, const float* __restrict__ nw,
    const float* __restrict__ nb, u16* __restrict__ h) {
  const int bx = blockIdx.x;
  const int tid = threadIdx.x;
  if (bx < 6464) {
    const int q = bx * 256 + tid;
    const float4* src;
    ushort4* dst;
    int off;
    if (q < 1048576) { src = (const float4*)w0; dst = (ushort4*)o0; off = q; }
    else if (q < 1097728) { src = (const float4*)w1; dst = (ushort4*)o1; off = q - 1048576; }
    else if (q < 1130496) { src = (const float4*)w2; dst = (ushort4*)o2; off = q - 1097728; }
    else { src = (const float4*)w3; dst = (ushort4*)o3; off = q - 1130496; }
    const float4 v = src[off];
    ushort4 o;
    o.x = f2bf(v.x); o.y = f2bf(v.y); o.z = f2bf(v.z); o.w = f2bf(v.w);
    dst[off] = o;
    return;
  }
  const int row = bx - 6464;
  const float4 v = ((const float4*)(x + (size_t)row * 1024))[tid];
  float s = v.x + v.y + v.z + v.w;
  float s2 = v.x * v.x + v.y * v.y + v.z * v.z + v.w * v.w;
  for (int off = 32; off >= 1; off >>= 1) {
    s += __shfl_xor(s, off);
    s2 += __shfl_xor(s2, off);
  }
  __shared__ float red[8];
  const int wave = tid >> 6;
  if ((tid & 63) == 0) { red[wave * 2] = s; red[wave * 2 + 1] = s2; }
  __syncthreads();
  s = red[0] + red[2] + red[4] + red[6];
  s2 = red[1] + red[3] + red[5] + red[7];
  const float mu = s * (1.0f / 1024.0f);
  const float var = s2 * (1.0f / 1024.0f) - mu * mu;
  const float rstd = rsqrtf(var + 1e-5f);
  const float4 wv = ((const float4*)nw)[tid];
  const float4 bv = ((const float4*)nb)[tid];
  ushort4 o;
  o.x = f2bf((v.x - mu) * rstd * wv.x + bv.x);
  o.y = f2bf((v.y - mu) * rstd * wv.y + bv.y);
  o.z = f2bf((v.z - mu) * rstd * wv.z + bv.z);
  o.w = f2bf((v.w - mu) * rstd * wv.w + bv.w);
  ((ushort4*)(h + (size_t)row * 1024))[tid] = o;
}

// ---------------- gemm128 tile body (m97 structure), bf16 out ---------------
__device__ __forceinline__ void gemm128_body(
    const u16* A, const u16* W, u16* Cout, int N, int K,
    int m0, int n0, int kOff, int kLen, size_t outBase, u16* As, u16* Ws) {
  const int tid = threadIdx.x;
  const int wave = tid >> 6;
  const int lane = tid & 63;
  const int wm = (wave >> 1) * 64;
  const int wn = (wave & 1) * 64;
  f32x4 acc[4][4];
#pragma unroll
  for (int i = 0; i < 4; ++i)
#pragma unroll
    for (int j = 0; j < 4; ++j) acc[i][j] = (f32x4){0.f, 0.f, 0.f, 0.f};
  const int fm = lane & 15;
  const int fk = (lane >> 4) * 8;
  const int sr = lane >> 2;
  const int sc = (lane & 3) * 8;
  const u16* gA = A + (size_t)(m0 + wave * 32 + sr) * K + kOff + sc;
  const u16* gB = W + (size_t)(n0 + wave * 32 + sr) * K + kOff + sc;
  u16* lA = As + wave * 1024;
  u16* lB = Ws + wave * 1024;

  for (int kk = 0; kk < kLen; kk += 32) {
    __syncthreads();
    lds_load16(gA + kk, lA);
    lds_load16(gA + (size_t)16 * K + kk, lA + 512);
    lds_load16(gB + kk, lB);
    lds_load16(gB + (size_t)16 * K + kk, lB + 512);
    __syncthreads();
    bf16x8 af[4], bfr[4];
#pragma unroll
    for (int i = 0; i < 4; ++i)
      af[i] = *(const bf16x8*)(As + (wm + i * 16 + fm) * 32 + fk);
#pragma unroll
    for (int j = 0; j < 4; ++j)
      bfr[j] = *(const bf16x8*)(Ws + (wn + j * 16 + fm) * 32 + fk);
#pragma unroll
    for (int i = 0; i < 4; ++i)
#pragma unroll
      for (int j = 0; j < 4; ++j)
        acc[i][j] = __builtin_amdgcn_mfma_f32_16x16x32_bf16(af[i], bfr[j], acc[i][j], 0, 0, 0);
  }
  const int col = lane & 15;
  const int rb = (lane >> 4) * 4;
#pragma unroll
  for (int i = 0; i < 4; ++i)
#pragma unroll
    for (int j = 0; j < 4; ++j)
#pragma unroll
      for (int r = 0; r < 4; ++r) {
        const int m = m0 + wm + i * 16 + rb + r;
        const int n = n0 + wn + j * 16 + col;
        Cout[outBase + (size_t)m * N + n] = f2bf(acc[i][j][r]);
      }
}

// k2: in_proj direct (SPLITK=1) / k9: out_proj slabs (SPLITK=4)
template <int SPLITK>
__global__ __launch_bounds__(256) void gemm128_kernel(
    const u16* __restrict__ A, const u16* __restrict__ W,
    u16* __restrict__ Cout, int M, int N, int K) {
  const int n0 = blockIdx.x * 128;
  const int m0 = blockIdx.y * 128;
  const int ks = (SPLITK > 1) ? blockIdx.z : 0;
  const int kLen = K / SPLITK;
  __shared__ u16 As[128 * 32];
  __shared__ u16 Ws[128 * 32];
  gemm128_body(A, W, Cout, N, K, m0, n0, ks * kLen, kLen,
               (SPLITK > 1) ? (size_t)ks * M * N : 0, As, Ws);
}

// ---------------- k3: conv + silu, vec4 channels ----------------
__global__ __launch_bounds__(256) void conv_silu_kernel(
    const u16* __restrict__ xzb, const float* __restrict__ cw,
    const float* __restrict__ cb, u16* __restrict__ xcb) {
  const int u = blockIdx.x * 256 + threadIdx.x;  // over M * 512
  const int d4 = (u & 511) * 4;
  const int m = u >> 9;
  const int l = m & 1023;
  const float4 wv0 = ((const float4*)cw)[d4];
  const float4 wv1 = ((const float4*)cw)[d4 + 1];
  const float4 wv2 = ((const float4*)cw)[d4 + 2];
  const float4 wv3 = ((const float4*)cw)[d4 + 3];
  const float4 cbv = ((const float4*)cb)[u & 511];
  float a0 = cbv.x, a1 = cbv.y, a2 = cbv.z, a3 = cbv.w;
  const float wk[4][4] = {{wv0.x, wv0.y, wv0.z, wv0.w},
                          {wv1.x, wv1.y, wv1.z, wv1.w},
                          {wv2.x, wv2.y, wv2.z, wv2.w},
                          {wv3.x, wv3.y, wv3.z, wv3.w}};
#pragma unroll
  for (int k = 0; k < 4; ++k) {
    if (l + k - 3 >= 0) {
      const ushort4 xv = *(const ushort4*)&xzb[(size_t)(m + k - 3) * 4096 + d4];
      a0 += bf2f(xv.x) * wk[0][k];
      a1 += bf2f(xv.y) * wk[1][k];
      a2 += bf2f(xv.z) * wk[2][k];
      a3 += bf2f(xv.w) * wk[3][k];
    }
  }
  ushort4 o;
  o.x = f2bf(a0 / (1.0f + __expf(-a0)));
  o.y = f2bf(a1 / (1.0f + __expf(-a1)));
  o.z = f2bf(a2 / (1.0f + __expf(-a2)));
  o.w = f2bf(a3 / (1.0f + __expf(-a3)));
  *(ushort4*)&xcb[(size_t)m * 2048 + d4] = o;
}

// ---------------- k4: x_proj 64-tile splitK4 -> f32 slabs ----------------
__global__ __launch_bounds__(256) void gemm_bt_kernel(
    const u16* __restrict__ A, const u16* __restrict__ W,
    float* __restrict__ C, int M, int N, int K) {
  const int n0 = blockIdx.x * 64;
  const int m0 = blockIdx.y * 64;
  const int ks = blockIdx.z;
  const int kLen = K / 4;
  const int kOff = ks * kLen;
  __shared__ u16 As[64 * 32];
  __shared__ u16 Ws[64 * 32];
  const int tid = threadIdx.x;
  const int wave = tid >> 6;
  const int lane = tid & 63;
  const int wm = (wave >> 1) * 32;
  const int wn = (wave & 1) * 32;
  const int lrow = tid >> 2;
  const int lcg = (tid & 3) * 8;
  f32x4 acc[2][2];
#pragma unroll
  for (int i = 0; i < 2; ++i)
#pragma unroll
    for (int j = 0; j < 2; ++j) acc[i][j] = (f32x4){0.f, 0.f, 0.f, 0.f};
  const int fm = lane & 15;
  const int fk = (lane >> 4) * 8;
  const int wrow = n0 + lrow;
  for (int k0 = kOff; k0 < kOff + kLen; k0 += 32) {
    uint4 av = *(const uint4*)(A + (size_t)(m0 + lrow) * K + k0 + lcg);
    uint4 wv = make_uint4(0u, 0u, 0u, 0u);
    if (wrow < N) wv = *(const uint4*)(W + (size_t)wrow * K + k0 + lcg);
    __syncthreads();
    *(uint4*)(As + lrow * 32 + lcg) = av;
    *(uint4*)(Ws + lrow * 32 + lcg) = wv;
    __syncthreads();
    bf16x8 a0 = *(const bf16x8*)(As + (wm + fm) * 32 + fk);
    bf16x8 a1 = *(const bf16x8*)(As + (wm + 16 + fm) * 32 + fk);
    bf16x8 b0 = *(const bf16x8*)(Ws + (wn + fm) * 32 + fk);
    bf16x8 b1 = *(const bf16x8*)(Ws + (wn + 16 + fm) * 32 + fk);
    acc[0][0] = __builtin_amdgcn_mfma_f32_16x16x32_bf16(a0, b0, acc[0][0], 0, 0, 0);
    acc[0][1] = __builtin_amdgcn_mfma_f32_16x16x32_bf16(a0, b1, acc[0][1], 0, 0, 0);
    acc[1][0] = __builtin_amdgcn_mfma_f32_16x16x32_bf16(a1, b0, acc[1][0], 0, 0, 0);
    acc[1][1] = __builtin_amdgcn_mfma_f32_16x16x32_bf16(a1, b1, acc[1][1], 0, 0, 0);
  }
  const int col = lane & 15;
  const int rbase = (lane >> 4) * 4;
#pragma unroll
  for (int tm = 0; tm < 2; ++tm)
#pragma unroll
    for (int tn = 0; tn < 2; ++tn)
#pragma unroll
      for (int r = 0; r < 4; ++r) {
        int m = m0 + wm + tm * 16 + rbase + r;
        int n = n0 + wn + tn * 16 + col;
        if (n < N)
          C[(size_t)ks * M * N + (size_t)m * N + n] = acc[tm][tn][r];
      }
}

// ---------------- k5: dt GEMM fused (comb + softplus -> bf16 dt) ------------
__global__ __launch_bounds__(256) void dtgemm_fused_kernel(
    const float* __restrict__ xpart, const u16* __restrict__ Wdt,
    const float* __restrict__ bias, u16* __restrict__ dtb,
    float* __restrict__ xdbl) {
  const int K = 64;
  const int n0 = blockIdx.x * 64;
  const int m0 = blockIdx.y * 64;
  const int tid = threadIdx.x;
  if (blockIdx.x == 0) {
#pragma unroll
    for (int j = 0; j < 8; ++j) {
      const int e = tid * 8 + j;
      const size_t ix = (size_t)(m0 + (e >> 5)) * 96 + 64 + (e & 31);
      xdbl[ix] = xpart[ix] + xpart[ix + 196608] + xpart[ix + 2 * 196608] +
                 xpart[ix + 3 * 196608];
    }
  }
  __shared__ u16 As[64 * 32];
  __shared__ u16 Ws[64 * 32];
  const int wave = tid >> 6;
  const int lane = tid & 63;
  const int wm = (wave >> 1) * 32;
  const int wn = (wave & 1) * 32;
  const int lrow = tid >> 2;
  const int lcg = (tid & 3) * 8;
  f32x4 acc[2][2];
#pragma unroll
  for (int i = 0; i < 2; ++i)
#pragma unroll
    for (int j = 0; j < 2; ++j) acc[i][j] = (f32x4){0.f, 0.f, 0.f, 0.f};
  const int fm = lane & 15;
  const int fk = (lane >> 4) * 8;
  for (int k0 = 0; k0 < K; k0 += 32) {
    const size_t ab = (size_t)(m0 + lrow) * 96 + k0 + lcg;
    float av[8];
#pragma unroll
    for (int t = 0; t < 2; ++t) {
      float4 v0 = *(const float4*)&xpart[ab + t * 4];
      float4 v1 = *(const float4*)&xpart[ab + 196608 + t * 4];
      float4 v2 = *(const float4*)&xpart[ab + 2 * 196608 + t * 4];
      float4 v3 = *(const float4*)&xpart[ab + 3 * 196608 + t * 4];
      av[t * 4 + 0] = v0.x + v1.x + v2.x + v3.x;
      av[t * 4 + 1] = v0.y + v1.y + v2.y + v3.y;
      av[t * 4 + 2] = v0.z + v1.z + v2.z + v3.z;
      av[t * 4 + 3] = v0.w + v1.w + v2.w + v3.w;
    }
    ushort4 ap0, ap1;
    ap0.x = f2bf(av[0]); ap0.y = f2bf(av[1]); ap0.z = f2bf(av[2]); ap0.w = f2bf(av[3]);
    ap1.x = f2bf(av[4]); ap1.y = f2bf(av[5]); ap1.z = f2bf(av[6]); ap1.w = f2bf(av[7]);
    uint4 wv = *(const uint4*)(Wdt + (size_t)(n0 + lrow) * K + k0 + lcg);
    __syncthreads();
    *(ushort4*)(As + lrow * 32 + lcg) = ap0;
    *(ushort4*)(As + lrow * 32 + lcg + 4) = ap1;
    *(uint4*)(Ws + lrow * 32 + lcg) = wv;
    __syncthreads();
    bf16x8 a0 = *(const bf16x8*)(As + (wm + fm) * 32 + fk);
    bf16x8 a1 = *(const bf16x8*)(As + (wm + 16 + fm) * 32 + fk);
    bf16x8 b0 = *(const bf16x8*)(Ws + (wn + fm) * 32 + fk);
    bf16x8 b1 = *(const bf16x8*)(Ws + (wn + 16 + fm) * 32 + fk);
    acc[0][0] = __builtin_amdgcn_mfma_f32_16x16x32_bf16(a0, b0, acc[0][0], 0, 0, 0);
    acc[0][1] = __builtin_amdgcn_mfma_f32_16x16x32_bf16(a0, b1, acc[0][1], 0, 0, 0);
    acc[1][0] = __builtin_amdgcn_mfma_f32_16x16x32_bf16(a1, b0, acc[1][0], 0, 0, 0);
    acc[1][1] = __builtin_amdgcn_mfma_f32_16x16x32_bf16(a1, b1, acc[1][1], 0, 0, 0);
  }
  const int col = lane & 15;
  const int rbase = (lane >> 4) * 4;
#pragma unroll
  for (int tm = 0; tm < 2; ++tm)
#pragma unroll
    for (int tn = 0; tn < 2; ++tn)
#pragma unroll
      for (int r = 0; r < 4; ++r) {
        const int m = m0 + wm + tm * 16 + rbase + r;
        const int n = n0 + wn + tn * 16 + col;
        float v = acc[tm][tn][r] + bias[n];
        v = (v > 20.f) ? v : log1pf(__expf(v));
        dtb[(size_t)m * 2048 + n] = f2bf(v);
      }
}

// ---------------- k6-k8: register-state chunked scan ----------------
__global__ __launch_bounds__(256) void scan_pass1_kernel(
    const u16* __restrict__ dtb, const u16* __restrict__ xcb,
    const float* __restrict__ xdbl, const float* __restrict__ A_log,
    float* __restrict__ hend, float* __restrict__ prodA) {
  const int bx = blockIdx.x;
  const int d0 = (bx & 7) * 256;
  const int b = (bx >> 3) & 1;
  const int g = bx >> 4;
  const int tid = threadIdx.x;
  const int d = d0 + tid;
  const int mb = b * 1024 + g * SCAN_T;
  float a2[16];
#pragma unroll
  for (int q = 0; q < 4; ++q) {
    float4 al = *(const float4*)&A_log[(size_t)d * 16 + q * 4];
    a2[q * 4 + 0] = -__expf(al.x) * LOG2E;
    a2[q * 4 + 1] = -__expf(al.y) * LOG2E;
    a2[q * 4 + 2] = -__expf(al.z) * LOG2E;
    a2[q * 4 + 3] = -__expf(al.w) * LOG2E;
  }
  float h[16];
#pragma unroll
  for (int n = 0; n < 16; ++n) h[n] = 0.f;
  float cs = 0.f;
  const u16* dp = dtb + (size_t)mb * 2048 + d;
  const u16* xp = xcb + (size_t)mb * 2048 + d;
  const float* xb = xdbl + (size_t)mb * 96 + 64;
#pragma unroll 4
  for (int s = 0; s < SCAN_T; ++s) {
    const float dtv = bf2f(dp[(size_t)s * 2048]);
    const float xcv = bf2f(xp[(size_t)s * 2048]);
    const float du = dtv * xcv;
    const float4 B0 = *(const float4*)(xb + (size_t)s * 96 + 0);
    const float4 B1 = *(const float4*)(xb + (size_t)s * 96 + 4);
    const float4 B2 = *(const float4*)(xb + (size_t)s * 96 + 8);
    const float4 B3 = *(const float4*)(xb + (size_t)s * 96 + 12);
    const float Bv[16] = {B0.x, B0.y, B0.z, B0.w, B1.x, B1.y, B1.z, B1.w,
                          B2.x, B2.y, B2.z, B2.w, B3.x, B3.y, B3.z, B3.w};
#pragma unroll
    for (int n = 0; n < 16; ++n) {
      const float da = EXP2F(dtv * a2[n]);
      h[n] = __builtin_fmaf(da, h[n], du * Bv[n]);
    }
    cs += dtv;
  }
  const size_t base = ((size_t)(g * 2 + b) * 2048 + d) * 16;
#pragma unroll
  for (int q = 0; q < 4; ++q) {
    float4 hv = {h[q * 4], h[q * 4 + 1], h[q * 4 + 2], h[q * 4 + 3]};
    *(float4*)&hend[base + q * 4] = hv;
    float4 pv = {EXP2F(a2[q * 4] * cs), EXP2F(a2[q * 4 + 1] * cs),
                 EXP2F(a2[q * 4 + 2] * cs), EXP2F(a2[q * 4 + 3] * cs)};
    *(float4*)&prodA[base + q * 4] = pv;
  }
}

__global__ __launch_bounds__(256) void scan_combine_kernel(
    const float* __restrict__ hend, const float* __restrict__ prodA,
    float* __restrict__ hinit) {
  const int sid = blockIdx.x * 256 + threadIdx.x;
  float H = 0.f;
#pragma unroll 8
  for (int g = 0; g < SCAN_G; ++g) {
    hinit[g * NSTATE + sid] = H;
    H = prodA[g * NSTATE + sid] * H + hend[g * NSTATE + sid];
  }
}

__global__ __launch_bounds__(256) void scan_pass2_kernel(
    const u16* __restrict__ dtb, const u16* __restrict__ xcb,
    const u16* __restrict__ xzb, const float* __restrict__ xdbl,
    const float* __restrict__ A_log, const float* __restrict__ Dsk,
    const float* __restrict__ hinit, u16* __restrict__ yb) {
  const int bx = blockIdx.x;
  const int d0 = (bx & 7) * 256;
  const int b = (bx >> 3) & 1;
  const int g = bx >> 4;
  const int tid = threadIdx.x;
  const int d = d0 + tid;
  const int mb = b * 1024 + g * SCAN_T;
  float a2[16];
#pragma unroll
  for (int q = 0; q < 4; ++q) {
    float4 al = *(const float4*)&A_log[(size_t)d * 16 + q * 4];
    a2[q * 4 + 0] = -__expf(al.x) * LOG2E;
    a2[q * 4 + 1] = -__expf(al.y) * LOG2E;
    a2[q * 4 + 2] = -__expf(al.z) * LOG2E;
    a2[q * 4 + 3] = -__expf(al.w) * LOG2E;
  }
  const float Dd = Dsk[d];
  float h[16];
  {
    const float* hi = hinit + ((size_t)(g * 2 + b) * 2048 + d) * 16;
#pragma unroll
    for (int q = 0; q < 4; ++q) {
      float4 hv = *(const float4*)(hi + q * 4);
      h[q * 4] = hv.x; h[q * 4 + 1] = hv.y; h[q * 4 + 2] = hv.z; h[q * 4 + 3] = hv.w;
    }
  }
  const u16* dp = dtb + (size_t)mb * 2048 + d;
  const u16* xp = xcb + (size_t)mb * 2048 + d;
  const u16* zp = xzb + (size_t)mb * 4096 + 2048 + d;
  const float* xb = xdbl + (size_t)mb * 96 + 64;
  u16* yp = yb + (size_t)mb * 2048 + d;
#pragma unroll 2
  for (int s = 0; s < SCAN_T; ++s) {
    const float dtv = bf2f(dp[(size_t)s * 2048]);
    const float xcv = bf2f(xp[(size_t)s * 2048]);
    const float du = dtv * xcv;
    const float4 B0 = *(const float4*)(xb + (size_t)s * 96 + 0);
    const float4 B1 = *(const float4*)(xb + (size_t)s * 96 + 4);
    const float4 B2 = *(const float4*)(xb + (size_t)s * 96 + 8);
    const float4 B3 = *(const float4*)(xb + (size_t)s * 96 + 12);
    const float4 C0 = *(const float4*)(xb + (size_t)s * 96 + 16);
    const float4 C1 = *(const float4*)(xb + (size_t)s * 96 + 20);
    const float4 C2 = *(const float4*)(xb + (size_t)s * 96 + 24);
    const float4 C3 = *(const float4*)(xb + (size_t)s * 96 + 28);
    const float Bv[16] = {B0.x, B0.y, B0.z, B0.w, B1.x, B1.y, B1.z, B1.w,
                          B2.x, B2.y, B2.z, B2.w, B3.x, B3.y, B3.z, B3.w};
    const float Cv[16] = {C0.x, C0.y, C0.z, C0.w, C1.x, C1.y, C1.z, C1.w,
                          C2.x, C2.y, C2.z, C2.w, C3.x, C3.y, C3.z, C3.w};
    float y = 0.f;
#pragma unroll
    for (int n = 0; n < 16; ++n) {
      const float da = EXP2F(dtv * a2[n]);
      h[n] = __builtin_fmaf(da, h[n], du * Bv[n]);
      y = __builtin_fmaf(h[n], Cv[n], y);
    }
    const float zv = bf2f(zp[(size_t)s * 4096]);
    const float sig = 1.0f / (1.0f + EXP2F(-zv * LOG2E));
    const float yv = (y + xcv * Dd) * (zv * sig);
    yp[(size_t)s * 2048] = f2bf(yv);
  }
}

// ---------------- k10: out splitK combine -----------------------------------
__global__ __launch_bounds__(256) void out_comb_kernel(
    const u16* __restrict__ part, const float* __restrict__ x,
    float* __restrict__ out) {
  const int i4 = (blockIdx.x * 256 + threadIdx.x) * 4;
  const float4 xv = *(const float4*)&x[i4];
  float a0 = xv.x, a1 = xv.y, a2 = xv.z, a3 = xv.w;
#pragma unroll
  for (int ks = 0; ks < 4; ++ks) {
    ushort4 pv = *(const ushort4*)&part[(size_t)ks * 2097152 + i4];
    a0 += bf2f(pv.x); a1 += bf2f(pv.y); a2 += bf2f(pv.z); a3 += bf2f(pv.w);
  }
  float4 o = {a0, a1, a2, a3};
  *(float4*)&out[i4] = o;
}

// ---------------- launch ----------------
extern "C" void kernel_launch(void* const* d_in, const int* in_sizes, int n_in,
                              void* d_out, int out_size, void* d_ws, size_t ws_size,
                              hipStream_t stream) {
  const float* x        = (const float*)d_in[0];
  const float* norm_w   = (const float*)d_in[1];
  const float* norm_b   = (const float*)d_in[2];
  const float* in_projw = (const float*)d_in[3];
  const float* conv_w   = (const float*)d_in[4];
  const float* conv_b   = (const float*)d_in[5];
  const float* x_projw  = (const float*)d_in[6];
  const float* dt_projw = (const float*)d_in[7];
  const float* dt_projb = (const float*)d_in[8];
  const float* A_log    = (const float*)d_in[9];
  const float* D_skip   = (const float*)d_in[10];
  const float* out_projw= (const float*)d_in[11];
  float* out = (float*)d_out;

  char* p = (char*)d_ws;
  auto alloc = [&](size_t bytes) {
    char* r = p;
    p += (bytes + 255) & ~(size_t)255;
    return r;
  };
  u16* xzb    = (u16*)alloc(2048ULL * 4096 * 2);   // 16 MB (also out partials)
  u16* xcb    = (u16*)alloc(2048ULL * 2048 * 2);   // 8 MB
  u16* dtb16  = (u16*)alloc(2048ULL * 2048 * 2);   // 8 MB
  float* xdbl = (float*)alloc(2048ULL * 96 * 4);   // 768 KB
  u16* h_bf   = (u16*)alloc(2048ULL * 1024 * 2);   // 4 MB
  u16* ybf    = (u16*)alloc(2048ULL * 2048 * 2);   // 8 MB
  u16* Wi     = (u16*)alloc(4096ULL * 1024 * 2);   // 8 MB
  u16* Wx     = (u16*)alloc(96ULL * 2048 * 2);     // 384 KB
  u16* Wdt    = (u16*)alloc(2048ULL * 64 * 2);     // 256 KB
  u16* Wo     = (u16*)alloc(1024ULL * 2048 * 2);   // 4 MB
  float* hend = (float*)alloc((size_t)SCAN_G * NSTATE * 4);  // 8 MB
  float* prodA= (float*)alloc((size_t)SCAN_G * NSTATE * 4);  // 8 MB
  float* hinit= (float*)alloc((size_t)SCAN_G * NSTATE * 4);  // 8 MB
  float* xpart= (float*)alloc(4ULL * 2048 * 96 * 4);         // 3 MB
  u16* opart  = xzb;  // alias: xzb dead after scan_pass2
  (void)ws_size; (void)in_sizes; (void)n_in; (void)out_size;

  // k1: vec4 weight converts + layernorm
  convert_ln_kernel<<<8512, 256, 0, stream>>>(in_projw, x_projw, dt_projw,
                                              out_projw, Wi, Wx, Wdt, Wo,
                                              x, norm_w, norm_b, h_bf);

  // k2: xz = h @ in_proj_w^T  [2048,4096] -> bf16 (512 blocks)
  gemm128_kernel<1><<<dim3(32, 16), 256, 0, stream>>>(h_bf, Wi, xzb, 2048, 4096, 1024);

  // k3: conv + silu -> xc bf16 (vec4)
  conv_silu_kernel<<<4096, 256, 0, stream>>>(xzb, conv_w, conv_b, xcb);

  // k4: x_dbl partials = xc @ x_proj_w^T  [2048,96], splitK=4
  gemm_bt_kernel<<<dim3(2, 32, 4), 256, 0, stream>>>(xcb, Wx, xpart, 2048, 96, 2048);

  // k5: dt gemm fused (comb + softplus -> bf16 dt; writes xdbl B/C)
  dtgemm_fused_kernel<<<dim3(32, 32), 256, 0, stream>>>(xpart, Wdt, dt_projb,
                                                        dtb16, xdbl);

  // k6-k8: chunked selective scan
  scan_pass1_kernel<<<512, 256, 0, stream>>>(dtb16, xcb, xdbl, A_log, hend, prodA);
  scan_combine_kernel<<<256, 256, 0, stream>>>(hend, prodA, hinit);
  scan_pass2_kernel<<<512, 256, 0, stream>>>(dtb16, xcb, xzb, xdbl, A_log,
                                             D_skip, hinit, ybf);

  // k9: out partials = y @ out_proj_w^T  [2048,1024], splitK=4 (512 blocks)
  gemm128_kernel<4><<<dim3(8, 16, 4), 256, 0, stream>>>(ybf, Wo, opart, 2048, 1024, 2048);
  // k10: out = x + sum(partials)
  out_comb_kernel<<<2048, 256, 0, stream>>>(opart, x, out);
}